// Round 7
// baseline (2200.606 us; speedup 1.0000x reference)
//
#include <hip/hip_runtime.h>
#include <math.h>

#define N_NODES 50000
#define N_EDGES 100000
#define H 768
#define NH 12
#define HD 64
#define NG 64
#define NC 10
#define H2 384

typedef __attribute__((ext_vector_type(8))) short          bfrag;   // 8 bf16 (4 VGPR)
typedef __attribute__((ext_vector_type(4))) float          ffrag;   // MFMA acc

// ---------------- static device scratch ----------------
__device__ float          g_bufA[(size_t)N_NODES * H];
__device__ float          g_bufB[(size_t)N_NODES * H];
__device__ unsigned short g_ah[(size_t)N_NODES * H];   // activation hi bf16
__device__ unsigned short g_al[(size_t)N_NODES * H];   // activation lo bf16
__device__ unsigned short g_wh[H * H];                 // weight^T hi bf16 [N][K]
__device__ unsigned short g_wl[H * H];                 // weight^T lo bf16
__device__ float          g_dinv[N_NODES];
__device__ int            g_degi[N_NODES];
__device__ int            g_cursor[N_NODES];
__device__ int            g_rowptr[N_NODES + 1];
__device__ int            g_csrsrc[N_EDGES];
__device__ float          g_aS[(size_t)N_NODES * NH];
__device__ float          g_aD[(size_t)N_NODES * NH];
__device__ float          g_pool[NG * H];
__device__ float          g_zb[NG * H2];

__device__ inline int clampi(int v, int hi) { return (v < 0) ? 0 : (v >= hi ? hi - 1 : v); }

__device__ inline unsigned short bf16rn(float f) {
    unsigned u = __float_as_uint(f);
    unsigned r = u + 0x7fffu + ((u >> 16) & 1u);   // RNE; inputs finite
    return (unsigned short)(r >> 16);
}
__device__ inline float bf16f(unsigned short h) { return __uint_as_float((unsigned)h << 16); }

// async global->LDS, 16B per lane: lane i writes lds_base + i*16 (wave-uniform base)
__device__ inline void gload_lds16(const unsigned short* g, unsigned short* s) {
    __builtin_amdgcn_global_load_lds(
        (const __attribute__((address_space(1))) void*)g,
        (__attribute__((address_space(3))) void*)s, 16, 0, 0);
}

// ---------------- CSR build ----------------
__global__ void fill_i32(int* p, int n, int v) {
    int i = blockIdx.x * blockDim.x + threadIdx.x;
    if (i < n) p[i] = v;
}

__global__ void count_deg(const int* __restrict__ dst, int* __restrict__ degi) {
    int e = blockIdx.x * blockDim.x + threadIdx.x;
    if (e < N_EDGES) atomicAdd(&degi[clampi(dst[e], N_NODES)], 1);
}

__global__ void dinv_k(const int* __restrict__ degi, float* __restrict__ dinv) {
    int i = blockIdx.x * blockDim.x + threadIdx.x;
    if (i < N_NODES) dinv[i] = rsqrtf((float)degi[i] + 1.0f);   // +1 = self-loop
}

__global__ __launch_bounds__(1024) void scan_rowptr(const int* __restrict__ degi,
                                                    int* __restrict__ rowptr,
                                                    int* __restrict__ cursor) {
    __shared__ int buf[1024];
    __shared__ int carry;
    int tid = threadIdx.x;
    if (tid == 0) carry = 0;
    __syncthreads();
    for (int base = 0; base < N_NODES; base += 1024) {
        int idx = base + tid;
        int v = (idx < N_NODES) ? degi[idx] : 0;
        buf[tid] = v;
        __syncthreads();
        for (int off = 1; off < 1024; off <<= 1) {
            int t = (tid >= off) ? buf[tid - off] : 0;
            __syncthreads();
            buf[tid] += t;
            __syncthreads();
        }
        if (idx < N_NODES) {
            int excl = buf[tid] - v + carry;
            rowptr[idx] = excl;
            cursor[idx] = excl;
        }
        int total = buf[1023];
        __syncthreads();
        if (tid == 0) carry += total;
        __syncthreads();
    }
    if (tid == 0) rowptr[N_NODES] = carry;
}

__global__ void bin_edges(const int* __restrict__ src, const int* __restrict__ dst,
                          int* __restrict__ cursor, int* __restrict__ csrsrc) {
    int e = blockIdx.x * blockDim.x + threadIdx.x;
    if (e >= N_EDGES) return;
    int d = clampi(dst[e], N_NODES);
    int pos = atomicAdd(&cursor[d], 1);
    if (pos >= 0 && pos < N_EDGES) csrsrc[pos] = clampi(src[e], N_NODES);
}

// ---------------- GEMM: x@w1 (K=3) ----------------
__global__ void gemm_k3(const float* __restrict__ x, const float* __restrict__ w,
                        float* __restrict__ out) {
    int idx = blockIdx.x * blockDim.x + threadIdx.x;
    if (idx >= N_NODES * H) return;
    int n = idx / H, j = idx % H;
    float x0 = x[n*3], x1 = x[n*3+1], x2 = x[n*3+2];
    out[idx] = x0 * w[j] + x1 * w[H + j] + x2 * w[2*H + j];
}

// weights: w[K][N] fp32 -> transposed hi/lo bf16 [N][K]
__global__ void split_wT(const float* __restrict__ w, unsigned short* __restrict__ hi,
                         unsigned short* __restrict__ lo) {
    int idx = blockIdx.x * blockDim.x + threadIdx.x;   // over H*H
    if (idx >= H * H) return;
    int n = idx % H, k = idx / H;                      // read coalesced in n
    float v = w[(size_t)k * H + n];
    unsigned short h = bf16rn(v);
    hi[(size_t)n * H + k] = h;
    lo[(size_t)n * H + k] = bf16rn(v - bf16f(h));
}

// ---------------- bf16x3 MFMA GEMM, double-buffered ----------------
// C[M,768] = A[M,768] @ W; A,W pre-split bf16 hi/lo; W transposed [N][K].
// 128x128 tile, 256 threads (4 waves), wave = 64x64 via 4x4 of 16x16x32 MFMA.
// Round-6 evidence: stage->barrier back-to-back exposed full load latency each
// of 24 K-iters (MfmaUtil 27%, 210 of 286 us stall). Fix: double-buffered LDS;
// prefetch tile k+1 (async global_load_lds) BEFORE computing tile k, one
// barrier per iter. The vmcnt drain at the barrier now lands after the whole
// MFMA section. LDS 64 KB -> 2 blocks/CU (accepted: AGPR budget caps ~2-3).
__global__ __launch_bounds__(256) void gemm_bf16x3(const unsigned short* __restrict__ ah,
                                                   const unsigned short* __restrict__ al,
                                                   const unsigned short* __restrict__ bth,
                                                   const unsigned short* __restrict__ btl,
                                                   float* __restrict__ C, int M) {
    __shared__ unsigned short sAh[2][128 * 32], sAl[2][128 * 32];
    __shared__ unsigned short sBh[2][128 * 32], sBl[2][128 * 32];
    int tid = threadIdx.x;
    int wave = tid >> 6, lane = tid & 63;
    int quad = lane >> 4, l16 = lane & 15;

    int id = blockIdx.x;
    int x = id & 7;            // XCD slot (round-robin); strips grouped per-XCD
    int s = id >> 3;
    int strip = x + 8 * (s / 6);
    int colt = s % 6;
    if (strip >= (N_NODES + 127) / 128) return;
    int row0 = strip * 128, col0 = colt * 128;
    int wr = (wave >> 1) * 64, wc = (wave & 1) * 64;

    // this wave's staging assignment (wave-specialized)
    const unsigned short* gsrc;
    unsigned short* sdst0;
    unsigned short* sdst1;
    int gbase;
    if (wave == 0)      { gsrc = ah;  sdst0 = sAh[0]; sdst1 = sAh[1]; gbase = row0; }
    else if (wave == 1) { gsrc = al;  sdst0 = sAl[0]; sdst1 = sAl[1]; gbase = row0; }
    else if (wave == 2) { gsrc = bth; sdst0 = sBh[0]; sdst1 = sBh[1]; gbase = col0; }
    else                { gsrc = btl; sdst0 = sBl[0]; sdst1 = sBl[1]; gbase = col0; }
    int isA = (wave < 2);
    int rr = lane >> 2, kc = (lane & 3) << 3;   // 4 lanes per row, 8-ushort chunks

    // per-lane global base row (clamped once)
    int grow = gbase + rr;
    const unsigned short* gptr[8];
    #pragma unroll
    for (int seg = 0; seg < 8; seg++) {
        int r = grow + seg * 16;
        if (isA && r >= M) r = M - 1;   // clamped rows feed unstored C rows
        gptr[seg] = gsrc + (size_t)r * H + kc;
    }

    ffrag acc[4][4];
    #pragma unroll
    for (int i = 0; i < 4; i++)
        #pragma unroll
        for (int j = 0; j < 4; j++) { ffrag z = {0.f, 0.f, 0.f, 0.f}; acc[i][j] = z; }

    // prologue: stage k-tile 0 into buffer 0
    #pragma unroll
    for (int seg = 0; seg < 8; seg++)
        gload_lds16(gptr[seg], sdst0 + seg * 512);

    #pragma unroll 1
    for (int kt = 0; kt < H / 32; kt++) {
        int cur = kt & 1;
        __syncthreads();   // buf[cur] loads complete; prior reads of buf[cur] long done
        // prefetch next k-tile into the other buffer (fully async across compute)
        if (kt + 1 < H / 32) {
            unsigned short* nb = (cur ? sdst0 : sdst1);
            int koff = (kt + 1) * 32;
            #pragma unroll
            for (int seg = 0; seg < 8; seg++)
                gload_lds16(gptr[seg] + koff, nb + seg * 512);
        }

        const unsigned short* pAh = sAh[cur];
        const unsigned short* pAl = sAl[cur];
        const unsigned short* pBh = sBh[cur];
        const unsigned short* pBl = sBl[cur];
        bfrag fah[4], fal[4], fbh[4], fbl[4];
        #pragma unroll
        for (int i = 0; i < 4; i++) {
            int r = wr + i * 16 + l16;
            fah[i] = *reinterpret_cast<const bfrag*>(&pAh[r * 32 + quad * 8]);
            fal[i] = *reinterpret_cast<const bfrag*>(&pAl[r * 32 + quad * 8]);
        }
        #pragma unroll
        for (int j = 0; j < 4; j++) {
            int c = wc + j * 16 + l16;
            fbh[j] = *reinterpret_cast<const bfrag*>(&pBh[c * 32 + quad * 8]);
            fbl[j] = *reinterpret_cast<const bfrag*>(&pBl[c * 32 + quad * 8]);
        }
        #pragma unroll
        for (int i = 0; i < 4; i++)
            #pragma unroll
            for (int j = 0; j < 4; j++) {
                acc[i][j] = __builtin_amdgcn_mfma_f32_16x16x32_bf16(fah[i], fbh[j], acc[i][j], 0, 0, 0);
                acc[i][j] = __builtin_amdgcn_mfma_f32_16x16x32_bf16(fah[i], fbl[j], acc[i][j], 0, 0, 0);
                acc[i][j] = __builtin_amdgcn_mfma_f32_16x16x32_bf16(fal[i], fbh[j], acc[i][j], 0, 0, 0);
            }
    }

    // epilogue: C/D layout col=lane&15, row=quad*4+reg (m89-verified)
    #pragma unroll
    for (int i = 0; i < 4; i++)
        #pragma unroll
        for (int r = 0; r < 4; r++) {
            int row = row0 + wr + i * 16 + quad * 4 + r;
            if (row >= M) continue;
            #pragma unroll
            for (int j = 0; j < 4; j++)
                C[(size_t)row * H + col0 + wc + j * 16 + l16] = acc[i][j][r];
        }
}

// ---------------- fused GCN gather (self + edges + bias + relu + bf16 split) ----
__global__ void gcn_gather(const int* __restrict__ rowptr, const int* __restrict__ csrsrc,
                           const float* __restrict__ h, const float* __restrict__ dinv,
                           const float* __restrict__ bias,
                           unsigned short* __restrict__ hi, unsigned short* __restrict__ lo) {
    int d = blockIdx.x;
    int t = threadIdx.x;
    float dd = dinv[d];
    float4 v = ((const float4*)(h + (size_t)d * H))[t];
    float c = dd * dd;
    float4 acc; acc.x = v.x * c; acc.y = v.y * c; acc.z = v.z * c; acc.w = v.w * c;
    int beg = rowptr[d], end = rowptr[d + 1];
    for (int i = beg; i < end; i++) {
        int s = csrsrc[i];
        float cc = dinv[s] * dd;
        float4 u = ((const float4*)(h + (size_t)s * H))[t];
        acc.x += u.x * cc; acc.y += u.y * cc; acc.z += u.z * cc; acc.w += u.w * cc;
    }
    float4 b = ((const float4*)bias)[t];
    acc.x = fmaxf(acc.x + b.x, 0.f); acc.y = fmaxf(acc.y + b.y, 0.f);
    acc.z = fmaxf(acc.z + b.z, 0.f); acc.w = fmaxf(acc.w + b.w, 0.f);
    ushort4 h4, l4;
    h4.x = bf16rn(acc.x); l4.x = bf16rn(acc.x - bf16f(h4.x));
    h4.y = bf16rn(acc.y); l4.y = bf16rn(acc.y - bf16f(h4.y));
    h4.z = bf16rn(acc.z); l4.z = bf16rn(acc.z - bf16f(h4.z));
    h4.w = bf16rn(acc.w); l4.w = bf16rn(acc.w - bf16f(h4.w));
    ((ushort4*)(hi + (size_t)d * H))[t] = h4;
    ((ushort4*)(lo + (size_t)d * H))[t] = l4;
}

// ---------------- GAT ----------------
__global__ void gat_alpha(const float* __restrict__ h, const float* __restrict__ as,
                          const float* __restrict__ ad, float* __restrict__ alpha_s,
                          float* __restrict__ alpha_d) {
    int idx = blockIdx.x * blockDim.x + threadIdx.x;
    if (idx >= N_NODES * NH) return;
    int n = idx / NH, hh = idx % NH;
    const float* hp  = h  + (size_t)n * H + hh * HD;
    const float* asp = as + hh * HD;
    const float* adp = ad + hh * HD;
    float ss = 0.f, sd = 0.f;
    for (int k = 0; k < HD; k++) { float v = hp[k]; ss += v * asp[k]; sd += v * adp[k]; }
    alpha_s[idx] = ss; alpha_d[idx] = sd;
}

__device__ inline float lrelu(float v) { return (v > 0.f) ? v : 0.2f * v; }

// fused softmax + weighted aggregation + bias (+relu); one block per dst node.
__global__ void gat_gather(const int* __restrict__ rowptr, const int* __restrict__ csrsrc,
                           const float* __restrict__ h, const float* __restrict__ aS,
                           const float* __restrict__ aD, const float* __restrict__ bias,
                           float* __restrict__ out,
                           unsigned short* __restrict__ hi, unsigned short* __restrict__ lo,
                           int relu) {
    int d = blockIdx.x;
    int t = threadIdx.x;
    int hh = t >> 4;
    int beg = rowptr[d], end = rowptr[d + 1];
    float adv = aD[d * NH + hh];
    float eself = lrelu(aS[d * NH + hh] + adv);
    float m = eself;
    for (int i = beg; i < end; i++)
        m = fmaxf(m, lrelu(aS[csrsrc[i] * NH + hh] + adv));
    float ssum = __expf(eself - m);
    for (int i = beg; i < end; i++)
        ssum += __expf(lrelu(aS[csrsrc[i] * NH + hh] + adv) - m);
    float inv = 1.0f / ssum;
    float cself = __expf(eself - m) * inv;
    float4 v = ((const float4*)(h + (size_t)d * H))[t];
    float4 acc; acc.x = v.x * cself; acc.y = v.y * cself; acc.z = v.z * cself; acc.w = v.w * cself;
    for (int i = beg; i < end; i++) {
        int s = csrsrc[i];
        float c = __expf(lrelu(aS[s * NH + hh] + adv) - m) * inv;
        float4 u = ((const float4*)(h + (size_t)s * H))[t];
        acc.x += u.x * c; acc.y += u.y * c; acc.z += u.z * c; acc.w += u.w * c;
    }
    float4 b = ((const float4*)bias)[t];
    acc.x += b.x; acc.y += b.y; acc.z += b.z; acc.w += b.w;
    if (relu) {
        acc.x = fmaxf(acc.x, 0.f); acc.y = fmaxf(acc.y, 0.f);
        acc.z = fmaxf(acc.z, 0.f); acc.w = fmaxf(acc.w, 0.f);
    }
    if (hi) {
        ushort4 h4, l4;
        h4.x = bf16rn(acc.x); l4.x = bf16rn(acc.x - bf16f(h4.x));
        h4.y = bf16rn(acc.y); l4.y = bf16rn(acc.y - bf16f(h4.y));
        h4.z = bf16rn(acc.z); l4.z = bf16rn(acc.z - bf16f(h4.z));
        h4.w = bf16rn(acc.w); l4.w = bf16rn(acc.w - bf16f(h4.w));
        ((ushort4*)(hi + (size_t)d * H))[t] = h4;
        ((ushort4*)(lo + (size_t)d * H))[t] = l4;
    } else {
        ((float4*)(out + (size_t)d * H))[t] = acc;
    }
}

// ---------------- pooling (batch is sorted) + classifier ----------------
__device__ inline int lower_bound_i(const int* b, int n, int key) {
    int lo = 0, hi = n;
    while (lo < hi) { int mid = (lo + hi) >> 1; if (b[mid] < key) lo = mid + 1; else hi = mid; }
    return lo;
}

__global__ void pool_graph(const int* __restrict__ batch, const float* __restrict__ h,
                           float* __restrict__ pool) {
    int g = blockIdx.x;   // NG blocks, 192 threads
    int t = threadIdx.x;
    int lo = lower_bound_i(batch, N_NODES, g);
    int hi = lower_bound_i(batch, N_NODES, g + 1);
    float4 a0 = {0,0,0,0}, a1 = {0,0,0,0}, a2 = {0,0,0,0}, a3 = {0,0,0,0};
    int n = lo;
    for (; n + 3 < hi; n += 4) {
        float4 v0 = ((const float4*)(h + (size_t)(n+0) * H))[t];
        float4 v1 = ((const float4*)(h + (size_t)(n+1) * H))[t];
        float4 v2 = ((const float4*)(h + (size_t)(n+2) * H))[t];
        float4 v3 = ((const float4*)(h + (size_t)(n+3) * H))[t];
        a0.x += v0.x; a0.y += v0.y; a0.z += v0.z; a0.w += v0.w;
        a1.x += v1.x; a1.y += v1.y; a1.z += v1.z; a1.w += v1.w;
        a2.x += v2.x; a2.y += v2.y; a2.z += v2.z; a2.w += v2.w;
        a3.x += v3.x; a3.y += v3.y; a3.z += v3.z; a3.w += v3.w;
    }
    for (; n < hi; n++) {
        float4 v = ((const float4*)(h + (size_t)n * H))[t];
        a0.x += v.x; a0.y += v.y; a0.z += v.z; a0.w += v.w;
    }
    float inv = 1.0f / fmaxf((float)(hi - lo), 1.0f);
    float4 o;
    o.x = (a0.x + a1.x + a2.x + a3.x) * inv;
    o.y = (a0.y + a1.y + a2.y + a3.y) * inv;
    o.z = (a0.z + a1.z + a2.z + a3.z) * inv;
    o.w = (a0.w + a1.w + a2.w + a3.w) * inv;
    ((float4*)(pool + (size_t)g * H))[t] = o;
}

__global__ void mlp1(const float* __restrict__ g, const float* __restrict__ w,
                     const float* __restrict__ b, float* __restrict__ z) {
    int idx = blockIdx.x * blockDim.x + threadIdx.x;
    if (idx >= NG * H2) return;
    int gg = idx / H2, j = idx % H2;
    const float* gp = g + (size_t)gg * H;
    float acc = b[j];
    for (int k = 0; k < H; k++) acc += gp[k] * w[(size_t)k * H2 + j];
    z[idx] = fmaxf(acc, 0.f);
}

__global__ void mlp2(const float* __restrict__ z, const float* __restrict__ w,
                     const float* __restrict__ b, float* __restrict__ out) {
    int idx = blockIdx.x * blockDim.x + threadIdx.x;
    if (idx >= NG * NC) return;
    int gg = idx / NC, c = idx % NC;
    const float* zp = z + (size_t)gg * H2;
    float acc = b[c];
    for (int k = 0; k < H2; k++) acc += zp[k] * w[(size_t)k * NC + c];
    out[idx] = acc;
}

// ---------------- launch ----------------
extern "C" void kernel_launch(void* const* d_in, const int* in_sizes, int n_in,
                              void* d_out, int out_size, void* d_ws, size_t ws_size,
                              hipStream_t stream) {
    (void)d_ws; (void)ws_size;
    const float* x     = (const float*)d_in[0];
    const int*   ei    = (const int*)d_in[1];
    const int*   batch = (const int*)d_in[2];
    const float* w1  = (const float*)d_in[3];  const float* b1  = (const float*)d_in[4];
    const float* w2  = (const float*)d_in[5];  const float* b2  = (const float*)d_in[6];
    const float* w3  = (const float*)d_in[7];  const float* b3  = (const float*)d_in[8];
    const float* wg1 = (const float*)d_in[9];  const float* as1 = (const float*)d_in[10];
    const float* ad1 = (const float*)d_in[11]; const float* bg1 = (const float*)d_in[12];
    const float* wg2 = (const float*)d_in[13]; const float* as2 = (const float*)d_in[14];
    const float* ad2 = (const float*)d_in[15]; const float* bg2 = (const float*)d_in[16];
    const float* wc1 = (const float*)d_in[17]; const float* bc1 = (const float*)d_in[18];
    const float* wc2 = (const float*)d_in[19]; const float* bc2 = (const float*)d_in[20];

    const int* srcp = ei;            // edge_index[0]
    const int* dstp = ei + N_EDGES;  // edge_index[1]

    float *bufA, *bufB, *dinv, *aS, *aD, *pool, *zb;
    unsigned short *ah, *al, *wh, *wl;
    int *degi, *cursor, *rowptr, *csrsrc;
    hipGetSymbolAddress((void**)&bufA,   HIP_SYMBOL(g_bufA));
    hipGetSymbolAddress((void**)&bufB,   HIP_SYMBOL(g_bufB));
    hipGetSymbolAddress((void**)&ah,     HIP_SYMBOL(g_ah));
    hipGetSymbolAddress((void**)&al,     HIP_SYMBOL(g_al));
    hipGetSymbolAddress((void**)&wh,     HIP_SYMBOL(g_wh));
    hipGetSymbolAddress((void**)&wl,     HIP_SYMBOL(g_wl));
    hipGetSymbolAddress((void**)&dinv,   HIP_SYMBOL(g_dinv));
    hipGetSymbolAddress((void**)&degi,   HIP_SYMBOL(g_degi));
    hipGetSymbolAddress((void**)&cursor, HIP_SYMBOL(g_cursor));
    hipGetSymbolAddress((void**)&rowptr, HIP_SYMBOL(g_rowptr));
    hipGetSymbolAddress((void**)&csrsrc, HIP_SYMBOL(g_csrsrc));
    hipGetSymbolAddress((void**)&aS,     HIP_SYMBOL(g_aS));
    hipGetSymbolAddress((void**)&aD,     HIP_SYMBOL(g_aD));
    hipGetSymbolAddress((void**)&pool,   HIP_SYMBOL(g_pool));
    hipGetSymbolAddress((void**)&zb,     HIP_SYMBOL(g_zb));

    auto cdiv = [](int a, int b) { return (a + b - 1) / b; };
    // strips padded to 8-aligned (392) x 6 col tiles; kernel guards spill
    int ggrid = 8 * cdiv(cdiv(N_NODES, 128), 8) * (H / 128);   // 2352

    // ---- CSR build (per call; inputs re-restored each launch) ----
    fill_i32<<<cdiv(N_NODES,256),256,0,stream>>>(degi, N_NODES, 0);
    count_deg<<<cdiv(N_EDGES,256),256,0,stream>>>(dstp, degi);
    dinv_k<<<cdiv(N_NODES,256),256,0,stream>>>(degi, dinv);
    scan_rowptr<<<1,1024,0,stream>>>(degi, rowptr, cursor);
    bin_edges<<<cdiv(N_EDGES,256),256,0,stream>>>(srcp, dstp, cursor, csrsrc);

    // ---- GCN1 (K=3 GEMM stays fp32 vector) ----
    gemm_k3<<<cdiv(N_NODES*H,256),256,0,stream>>>(x, w1, bufA);
    gcn_gather<<<N_NODES,192,0,stream>>>(rowptr, csrsrc, bufA, dinv, b1, ah, al);

    // ---- GCN2 ----
    split_wT<<<cdiv(H*H,256),256,0,stream>>>(w2, wh, wl);
    gemm_bf16x3<<<ggrid,256,0,stream>>>(ah, al, wh, wl, bufA, N_NODES);
    gcn_gather<<<N_NODES,192,0,stream>>>(rowptr, csrsrc, bufA, dinv, b2, ah, al);

    // ---- GCN3 ----
    split_wT<<<cdiv(H*H,256),256,0,stream>>>(w3, wh, wl);
    gemm_bf16x3<<<ggrid,256,0,stream>>>(ah, al, wh, wl, bufA, N_NODES);
    gcn_gather<<<N_NODES,192,0,stream>>>(rowptr, csrsrc, bufA, dinv, b3, ah, al);

    // ---- GAT1 ----
    split_wT<<<cdiv(H*H,256),256,0,stream>>>(wg1, wh, wl);
    gemm_bf16x3<<<ggrid,256,0,stream>>>(ah, al, wh, wl, bufA, N_NODES);
    gat_alpha<<<cdiv(N_NODES*NH,256),256,0,stream>>>(bufA, as1, ad1, aS, aD);
    gat_gather<<<N_NODES,192,0,stream>>>(rowptr, csrsrc, bufA, aS, aD, bg1,
                                         (float*)nullptr, ah, al, 1);

    // ---- GAT2 (no relu; fp32 out for pooling) ----
    split_wT<<<cdiv(H*H,256),256,0,stream>>>(wg2, wh, wl);
    gemm_bf16x3<<<ggrid,256,0,stream>>>(ah, al, wh, wl, bufA, N_NODES);
    gat_alpha<<<cdiv(N_NODES*NH,256),256,0,stream>>>(bufA, as2, ad2, aS, aD);
    gat_gather<<<N_NODES,192,0,stream>>>(rowptr, csrsrc, bufA, aS, aD, bg2,
                                         bufB, (unsigned short*)nullptr, (unsigned short*)nullptr, 0);

    // ---- pool + classifier ----
    pool_graph<<<NG,192,0,stream>>>(batch, bufB, pool);
    mlp1<<<cdiv(NG*H2,256),256,0,stream>>>(pool, wc1, bc1, zb);
    mlp2<<<cdiv(NG*NC,64),64,0,stream>>>(zb, wc2, bc2, (float*)d_out);
}